// Round 7
// baseline (1010.978 us; speedup 1.0000x reference)
//
#include <hip/hip_runtime.h>
#include <hip/hip_bf16.h>

#define NN 100000
#define EE 800000
#define HH 4
#define CC 64
#define GG 2000
#define NB 98           // scan blocks: ceil((NN/4)/256)

// ---------------- CSR build ----------------

__global__ void hist_kernel(const int* __restrict__ ei, int* __restrict__ deg) {
    int e = blockIdx.x * 256 + threadIdx.x;
    const int tot = EE + NN;
    if (e < tot) {
        int d = (e < EE) ? ei[EE + e] : (e - EE);
        atomicAdd(&deg[d], 1);
    }
}

__global__ void node_count(const int* __restrict__ batch, float* __restrict__ pcnt) {
    int n = blockIdx.x * 256 + threadIdx.x;
    if (n < NN) atomicAdd(&pcnt[batch[n]], 1.0f);
}

// scan stage 1: per-block (1024 elems) sums, coalesced int4
__global__ __launch_bounds__(256) void scan_blk(const int* __restrict__ deg,
                                                int* __restrict__ bsum) {
    const int t = threadIdx.x;
    const int idx4 = blockIdx.x * 256 + t;
    int4 v = {0, 0, 0, 0};
    if (idx4 < NN / 4) v = ((const int4*)deg)[idx4];
    int s = v.x + v.y + v.z + v.w;
#pragma unroll
    for (int m = 32; m; m >>= 1) s += __shfl_xor(s, m, 64);
    __shared__ int ws[4];
    if ((t & 63) == 0) ws[t >> 6] = s;
    __syncthreads();
    if (t == 0) bsum[blockIdx.x] = ws[0] + ws[1] + ws[2] + ws[3];
}

__global__ void scan_mid(const int* __restrict__ bsum, int* __restrict__ boff,
                         int* __restrict__ off) {
    __shared__ int sh[128];
    const int t = threadIdx.x;
    int v = (t < NB) ? bsum[t] : 0;
    sh[t] = v;
    __syncthreads();
    for (int d = 1; d < 128; d <<= 1) {
        int u = (t >= d) ? sh[t - d] : 0;
        __syncthreads();
        sh[t] += u;
        __syncthreads();
    }
    if (t < NB) boff[t] = sh[t] - v;
    if (t == NB - 1) off[NN] = sh[t];
}

__global__ __launch_bounds__(256) void scan_fin(const int* __restrict__ deg,
                                                const int* __restrict__ boff,
                                                int* __restrict__ off) {
    const int t = threadIdx.x;
    const int idx4 = blockIdx.x * 256 + t;
    int4 v = {0, 0, 0, 0};
    if (idx4 < NN / 4) v = ((const int4*)deg)[idx4];
    int s = v.x + v.y + v.z + v.w;
    const int lane = t & 63, w = t >> 6;
    int inc = s;
#pragma unroll
    for (int d = 1; d < 64; d <<= 1) {
        int u = __shfl_up(inc, d, 64);
        if (lane >= d) inc += u;
    }
    __shared__ int ws[4];
    if (lane == 63) ws[w] = inc;
    __syncthreads();
    int woff = 0;
    for (int i = 0; i < w; ++i) woff += ws[i];
    int excl = inc - s + woff + boff[blockIdx.x];
    if (idx4 < NN / 4) {
        int4 o;
        o.x = excl;
        o.y = o.x + v.x;
        o.z = o.y + v.y;
        o.w = o.z + v.z;
        ((int4*)off)[idx4] = o;
    }
}

__global__ void fill_kernel(const int* __restrict__ ei, const int* __restrict__ off,
                            int* __restrict__ cursor, int* __restrict__ csr_src) {
    int e = blockIdx.x * 256 + threadIdx.x;
    const int tot = EE + NN;
    if (e < tot) {
        int s, d;
        if (e < EE) { s = ei[e]; d = ei[EE + e]; }
        else        { s = e - EE; d = e - EE; }
        int p = off[d] + atomicAdd(&cursor[d], 1);
        csr_src[p] = s;
    }
}

// ---------------- layer-1 GEMM (K=9) ----------------
// NOTE: the k-loop with step 3 and bound k+2<K covers k=0..8 COMPLETELY for
// K=9 (k=0,3,6 handle triplets {0,1,2},{3,4,5},{6,7,8}). No remainder term!
// (R6's bug: an extra wreg[8] FMA double-counted k=8.)

__global__ __launch_bounds__(256) void gemm_att9(
    const float* __restrict__ X, const float* __restrict__ W,
    const float* __restrict__ a_s, const float* __restrict__ a_d,
    float* __restrict__ Hb, float* __restrict__ ALS, float* __restrict__ ALD) {
    constexpr int K = 9, R = 2;
    const int c = threadIdx.x;
    const int lane = c & 63;
    const int wh = c >> 6;
    float wreg[K];
#pragma unroll
    for (int k = 0; k < K; ++k) wreg[k] = W[k * 256 + c];
    const float asv = a_s[c];
    const float adv = a_d[c];

    for (int row0 = blockIdx.x * R; row0 < NN; row0 += gridDim.x * R) {
        float p0[R], p1[R], p2[R];
#pragma unroll
        for (int r = 0; r < R; ++r) { p0[r] = p1[r] = p2[r] = 0.f; }
#pragma unroll
        for (int k = 0; k + 2 < K; k += 3) {
#pragma unroll
            for (int r = 0; r < R; ++r) {
                int rr = row0 + r; if (rr > NN - 1) rr = NN - 1;
                const float* xp = X + (size_t)rr * K;
                p0[r] = fmaf(wreg[k + 0], xp[k + 0], p0[r]);
                p1[r] = fmaf(wreg[k + 1], xp[k + 1], p1[r]);
                p2[r] = fmaf(wreg[k + 2], xp[k + 2], p2[r]);
            }
        }
#pragma unroll
        for (int r = 0; r < R; ++r) {
            int row = row0 + r;
            if (row < NN) {
                float hv = (p0[r] + p1[r]) + p2[r];
                Hb[(size_t)row * 256 + c] = hv;
                float sv = hv * asv;
                float dv = hv * adv;
#pragma unroll
                for (int m = 32; m; m >>= 1) {
                    sv += __shfl_xor(sv, m, 64);
                    dv += __shfl_xor(dv, m, 64);
                }
                if (lane == 0) {
                    ALS[row * 4 + wh] = sv;
                    ALD[row * 4 + wh] = dv;
                }
            }
        }
    }
}

// ---------------- K=64 GEMM: W resident in 64 VGPRs ----------------

__global__ __launch_bounds__(256) void gemm_att64(
    const float* __restrict__ X, const float* __restrict__ W,
    const float* __restrict__ a_s, const float* __restrict__ a_d,
    float* __restrict__ Hb, float* __restrict__ ALS, float* __restrict__ ALD) {
    constexpr int R = 4;
    const int c = threadIdx.x;
    const int lane = c & 63;
    const int wh = c >> 6;
    float4 w4[16];
#pragma unroll
    for (int q = 0; q < 16; ++q) {
        w4[q].x = W[(4 * q + 0) * 256 + c];
        w4[q].y = W[(4 * q + 1) * 256 + c];
        w4[q].z = W[(4 * q + 2) * 256 + c];
        w4[q].w = W[(4 * q + 3) * 256 + c];
    }
    const float asv = a_s[c];
    const float adv = a_d[c];

    for (int row0 = blockIdx.x * R; row0 < NN; row0 += gridDim.x * R) {
        float accA[R], accB[R];
#pragma unroll
        for (int r = 0; r < R; ++r) { accA[r] = accB[r] = 0.f; }
        // NN % R == 0 and stride % R == 0 -> rows row0..row0+R-1 always < NN
#pragma unroll
        for (int q = 0; q < 16; ++q) {
#pragma unroll
            for (int r = 0; r < R; ++r) {
                const float4 xv = ((const float4*)(X + (size_t)(row0 + r) * 64))[q];
                accA[r] = fmaf(w4[q].x, xv.x, accA[r]);
                accB[r] = fmaf(w4[q].y, xv.y, accB[r]);
                accA[r] = fmaf(w4[q].z, xv.z, accA[r]);
                accB[r] = fmaf(w4[q].w, xv.w, accB[r]);
            }
        }
#pragma unroll
        for (int r = 0; r < R; ++r) {
            int row = row0 + r;
            float hv = accA[r] + accB[r];
            Hb[(size_t)row * 256 + c] = hv;
            float sv = hv * asv;
            float dv = hv * adv;
#pragma unroll
            for (int m = 32; m; m >>= 1) {
                sv += __shfl_xor(sv, m, 64);
                dv += __shfl_xor(dv, m, 64);
            }
            if (lane == 0) {
                ALS[row * 4 + wh] = sv;
                ALD[row * 4 + wh] = dv;
            }
        }
    }
}

// ---------------- fused softmax + aggregate (+ optional pooling) ------------

template <bool LAST>
__global__ __launch_bounds__(256) void aggregate5(
    const float* __restrict__ Hb, const float* __restrict__ ALS,
    const float* __restrict__ ALD, const int* __restrict__ off,
    const int* __restrict__ csr_src, const float* __restrict__ bias,
    float* __restrict__ OUT, const int* __restrict__ batch,
    float* __restrict__ psum) {
    const int node = blockIdx.x * 4 + (threadIdx.x >> 6);
    const int l = threadIdx.x & 63;
    if (node >= NN) return;
    const int beg = off[node], end = off[node + 1];
    const int h = l >> 4;
    const float4* hb4 = (const float4*)Hb;
    const float4 aldv = ((const float4*)ALD)[node];
    float4 acc = {0.f, 0.f, 0.f, 0.f};
    float4 dsum = {0.f, 0.f, 0.f, 0.f};

    for (int j0 = beg; j0 < end; j0 += 64) {
        const int cnt = min(64, end - j0);
        const int jj = j0 + l;
        int sv = 0;
        float4 w4 = {0.f, 0.f, 0.f, 0.f};
        if (jj < end) {
            sv = csr_src[jj];
            float4 a = ((const float4*)ALS)[sv];
            float vx = a.x + aldv.x, vy = a.y + aldv.y,
                  vz = a.z + aldv.z, vw = a.w + aldv.w;
            vx = (vx >= 0.f) ? vx : 0.2f * vx;
            vy = (vy >= 0.f) ? vy : 0.2f * vy;
            vz = (vz >= 0.f) ? vz : 0.2f * vz;
            vw = (vw >= 0.f) ? vw : 0.2f * vw;
            w4.x = expf(vx); w4.y = expf(vy); w4.z = expf(vz); w4.w = expf(vw);
        }
        dsum.x += w4.x; dsum.y += w4.y; dsum.z += w4.z; dsum.w += w4.w;

        int t = 0;
        for (; t + 2 <= cnt; t += 2) {
            int s0 = __shfl(sv, t, 64);
            int s1 = __shfl(sv, t + 1, 64);
            float ax0 = __shfl(w4.x, t, 64), ay0 = __shfl(w4.y, t, 64),
                  az0 = __shfl(w4.z, t, 64), aw0 = __shfl(w4.w, t, 64);
            float ax1 = __shfl(w4.x, t + 1, 64), ay1 = __shfl(w4.y, t + 1, 64),
                  az1 = __shfl(w4.z, t + 1, 64), aw1 = __shfl(w4.w, t + 1, 64);
            float4 h0 = hb4[(size_t)s0 * 64 + l];
            float4 h1 = hb4[(size_t)s1 * 64 + l];
            float w0 = (h == 0) ? ax0 : (h == 1) ? ay0 : (h == 2) ? az0 : aw0;
            float w1 = (h == 0) ? ax1 : (h == 1) ? ay1 : (h == 2) ? az1 : aw1;
            acc.x = fmaf(w0, h0.x, acc.x); acc.y = fmaf(w0, h0.y, acc.y);
            acc.z = fmaf(w0, h0.z, acc.z); acc.w = fmaf(w0, h0.w, acc.w);
            acc.x = fmaf(w1, h1.x, acc.x); acc.y = fmaf(w1, h1.y, acc.y);
            acc.z = fmaf(w1, h1.z, acc.z); acc.w = fmaf(w1, h1.w, acc.w);
        }
        if (t < cnt) {
            int s0 = __shfl(sv, t, 64);
            float ax0 = __shfl(w4.x, t, 64), ay0 = __shfl(w4.y, t, 64),
                  az0 = __shfl(w4.z, t, 64), aw0 = __shfl(w4.w, t, 64);
            float4 h0 = hb4[(size_t)s0 * 64 + l];
            float w0 = (h == 0) ? ax0 : (h == 1) ? ay0 : (h == 2) ? az0 : aw0;
            acc.x = fmaf(w0, h0.x, acc.x); acc.y = fmaf(w0, h0.y, acc.y);
            acc.z = fmaf(w0, h0.z, acc.z); acc.w = fmaf(w0, h0.w, acc.w);
        }
    }

#pragma unroll
    for (int m = 32; m; m >>= 1) {
        dsum.x += __shfl_xor(dsum.x, m, 64);
        dsum.y += __shfl_xor(dsum.y, m, 64);
        dsum.z += __shfl_xor(dsum.z, m, 64);
        dsum.w += __shfl_xor(dsum.w, m, 64);
    }
    float den = (h == 0) ? dsum.x : (h == 1) ? dsum.y : (h == 2) ? dsum.z : dsum.w;
    const float inv = 1.f / (den + 1e-16f);
    acc.x *= inv; acc.y *= inv; acc.z *= inv; acc.w *= inv;

#pragma unroll
    for (int m = 16; m <= 32; m <<= 1) {
        acc.x += __shfl_xor(acc.x, m, 64);
        acc.y += __shfl_xor(acc.y, m, 64);
        acc.z += __shfl_xor(acc.z, m, 64);
        acc.w += __shfl_xor(acc.w, m, 64);
    }
    if (l < 16) {
        float4 b4 = ((const float4*)bias)[l];
        float4 o;
        o.x = fmaxf(acc.x * 0.25f + b4.x, 0.f);
        o.y = fmaxf(acc.y * 0.25f + b4.y, 0.f);
        o.z = fmaxf(acc.z * 0.25f + b4.z, 0.f);
        o.w = fmaxf(acc.w * 0.25f + b4.w, 0.f);
        if constexpr (LAST) {
            int g = batch[node];
            float* pp = psum + (size_t)g * 64 + l * 4;
            atomicAdd(pp + 0, o.x);
            atomicAdd(pp + 1, o.y);
            atomicAdd(pp + 2, o.z);
            atomicAdd(pp + 3, o.w);
        } else {
            ((float4*)(OUT + (size_t)node * 64))[l] = o;
        }
    }
}

// ---------------- final linear ----------------

__global__ void pool_out(const float* __restrict__ psum, const float* __restrict__ pcnt,
                         const float* __restrict__ lw, const float* __restrict__ lb,
                         float* __restrict__ out) {
    int g = blockIdx.x * 4 + (threadIdx.x >> 6);
    int lane = threadIdx.x & 63;
    if (g < GG) {
        float cnt = fmaxf(pcnt[g], 1.0f);
        float v = psum[(size_t)g * 64 + lane] / cnt * lw[lane];
#pragma unroll
        for (int m = 32; m; m >>= 1) v += __shfl_xor(v, m, 64);
        if (lane == 0) out[g] = v + lb[0];
    }
}

// ---------------- launch ----------------

extern "C" void kernel_launch(void* const* d_in, const int* in_sizes, int n_in,
                              void* d_out, int out_size, void* d_ws, size_t ws_size,
                              hipStream_t stream) {
    const float* x     = (const float*)d_in[0];
    const int*   ei    = (const int*)d_in[1];
    const int*   batch = (const int*)d_in[2];
    const float* W1  = (const float*)d_in[3];
    const float* as1 = (const float*)d_in[4];
    const float* ad1 = (const float*)d_in[5];
    const float* b1  = (const float*)d_in[6];
    const float* W2  = (const float*)d_in[7];
    const float* as2 = (const float*)d_in[8];
    const float* ad2 = (const float*)d_in[9];
    const float* b2  = (const float*)d_in[10];
    const float* W3  = (const float*)d_in[11];
    const float* as3 = (const float*)d_in[12];
    const float* ad3 = (const float*)d_in[13];
    const float* b3  = (const float*)d_in[14];
    const float* lw  = (const float*)d_in[15];
    const float* lb  = (const float*)d_in[16];
    float* out = (float*)d_out;

    char* p = (char*)d_ws;
    auto carve = [&](size_t bytes) -> void* {
        void* r = (void*)p;
        p += (bytes + 255) & ~(size_t)255;
        return r;
    };
    int*    off    = (int*)carve((NN + 4) * sizeof(int));
    int*    deg    = (int*)carve(NN * sizeof(int));
    int*    cursor = (int*)carve(NN * sizeof(int));
    int*    bsum   = (int*)carve(NB * sizeof(int));
    int*    boff   = (int*)carve(NB * sizeof(int));
    int*    csr    = (int*)carve((size_t)(EE + NN) * sizeof(int));
    float*  hbuf   = (float*)carve((size_t)NN * 256 * sizeof(float));
    float*  fa     = (float*)carve((size_t)NN * 64 * sizeof(float));
    float*  als    = (float*)carve((size_t)NN * 4 * sizeof(float));
    float*  ald    = (float*)carve((size_t)NN * 4 * sizeof(float));
    float*  psum   = (float*)carve((size_t)GG * 64 * sizeof(float));
    float*  pcnt   = (float*)carve(GG * sizeof(float));

    hipMemsetAsync(deg, 0, NN * sizeof(int), stream);
    hipMemsetAsync(cursor, 0, NN * sizeof(int), stream);
    hipMemsetAsync(psum, 0, (size_t)GG * 64 * sizeof(float), stream);
    hipMemsetAsync(pcnt, 0, GG * sizeof(float), stream);

    const int etot = EE + NN;
    const int eblocks = (etot + 255) / 256;
    hist_kernel<<<eblocks, 256, 0, stream>>>(ei, deg);
    node_count<<<(NN + 255) / 256, 256, 0, stream>>>(batch, pcnt);
    scan_blk<<<NB, 256, 0, stream>>>(deg, bsum);
    scan_mid<<<1, 128, 0, stream>>>(bsum, boff, off);
    scan_fin<<<NB, 256, 0, stream>>>(deg, boff, off);
    fill_kernel<<<eblocks, 256, 0, stream>>>(ei, off, cursor, csr);

    const int ablocks = (NN + 3) / 4;
    // layer 1
    gemm_att9<<<2048, 256, 0, stream>>>(x, W1, as1, ad1, hbuf, als, ald);
    aggregate5<false><<<ablocks, 256, 0, stream>>>(hbuf, als, ald, off, csr, b1,
                                                   fa, batch, psum);
    // layer 2
    gemm_att64<<<2048, 256, 0, stream>>>(fa, W2, as2, ad2, hbuf, als, ald);
    aggregate5<false><<<ablocks, 256, 0, stream>>>(hbuf, als, ald, off, csr, b2,
                                                   fa, batch, psum);
    // layer 3 (pooling fused)
    gemm_att64<<<2048, 256, 0, stream>>>(fa, W3, as3, ad3, hbuf, als, ald);
    aggregate5<true><<<ablocks, 256, 0, stream>>>(hbuf, als, ald, off, csr, b3,
                                                  nullptr, batch, psum);

    pool_out<<<(GG + 3) / 4, 256, 0, stream>>>(psum, pcnt, lw, lb, out);
}

// Round 8
// 825.544 us; speedup vs baseline: 1.2246x; 1.2246x over previous
//
#include <hip/hip_runtime.h>
#include <hip/hip_bf16.h>

#define NN 100000
#define EE 800000
#define HH 4
#define CC 64
#define GG 2000
#define NB 98           // scan blocks: ceil((NN/4)/256)

typedef unsigned short ushortx;
typedef unsigned int uintx;

// ---------------- CSR build ----------------

__global__ void hist_kernel(const int* __restrict__ ei, int* __restrict__ deg) {
    int e = blockIdx.x * 256 + threadIdx.x;
    const int tot = EE + NN;
    if (e < tot) {
        int d = (e < EE) ? ei[EE + e] : (e - EE);
        atomicAdd(&deg[d], 1);
    }
}

__global__ void node_count(const int* __restrict__ batch, float* __restrict__ pcnt) {
    int n = blockIdx.x * 256 + threadIdx.x;
    if (n < NN) atomicAdd(&pcnt[batch[n]], 1.0f);
}

__global__ __launch_bounds__(256) void scan_blk(const int* __restrict__ deg,
                                                int* __restrict__ bsum) {
    const int t = threadIdx.x;
    const int idx4 = blockIdx.x * 256 + t;
    int4 v = {0, 0, 0, 0};
    if (idx4 < NN / 4) v = ((const int4*)deg)[idx4];
    int s = v.x + v.y + v.z + v.w;
#pragma unroll
    for (int m = 32; m; m >>= 1) s += __shfl_xor(s, m, 64);
    __shared__ int ws[4];
    if ((t & 63) == 0) ws[t >> 6] = s;
    __syncthreads();
    if (t == 0) bsum[blockIdx.x] = ws[0] + ws[1] + ws[2] + ws[3];
}

__global__ void scan_mid(const int* __restrict__ bsum, int* __restrict__ boff,
                         int* __restrict__ off) {
    __shared__ int sh[128];
    const int t = threadIdx.x;
    int v = (t < NB) ? bsum[t] : 0;
    sh[t] = v;
    __syncthreads();
    for (int d = 1; d < 128; d <<= 1) {
        int u = (t >= d) ? sh[t - d] : 0;
        __syncthreads();
        sh[t] += u;
        __syncthreads();
    }
    if (t < NB) boff[t] = sh[t] - v;
    if (t == NB - 1) off[NN] = sh[t];
}

__global__ __launch_bounds__(256) void scan_fin(const int* __restrict__ deg,
                                                const int* __restrict__ boff,
                                                int* __restrict__ off) {
    const int t = threadIdx.x;
    const int idx4 = blockIdx.x * 256 + t;
    int4 v = {0, 0, 0, 0};
    if (idx4 < NN / 4) v = ((const int4*)deg)[idx4];
    int s = v.x + v.y + v.z + v.w;
    const int lane = t & 63, w = t >> 6;
    int inc = s;
#pragma unroll
    for (int d = 1; d < 64; d <<= 1) {
        int u = __shfl_up(inc, d, 64);
        if (lane >= d) inc += u;
    }
    __shared__ int ws[4];
    if (lane == 63) ws[w] = inc;
    __syncthreads();
    int woff = 0;
    for (int i = 0; i < w; ++i) woff += ws[i];
    int excl = inc - s + woff + boff[blockIdx.x];
    if (idx4 < NN / 4) {
        int4 o;
        o.x = excl;
        o.y = o.x + v.x;
        o.z = o.y + v.y;
        o.w = o.z + v.z;
        ((int4*)off)[idx4] = o;
    }
}

__global__ void fill_kernel(const int* __restrict__ ei, const int* __restrict__ off,
                            int* __restrict__ cursor, int* __restrict__ csr_src) {
    int e = blockIdx.x * 256 + threadIdx.x;
    const int tot = EE + NN;
    if (e < tot) {
        int s, d;
        if (e < EE) { s = ei[e]; d = ei[EE + e]; }
        else        { s = e - EE; d = e - EE; }
        int p = off[d] + atomicAdd(&cursor[d], 1);
        csr_src[p] = s;
    }
}

__device__ __forceinline__ ushortx f2bf(float v) {
    __hip_bfloat16 b = __float2bfloat16(v);
    return *reinterpret_cast<ushortx*>(&b);
}

// ---------------- layer-1 GEMM (K=9) ----------------
// k-loop (step 3, bound k+2<K) covers k=0..8 COMPLETELY for K=9. No remainder.

__global__ __launch_bounds__(256) void gemm_att9(
    const float* __restrict__ X, const float* __restrict__ W,
    const float* __restrict__ a_s, const float* __restrict__ a_d,
    ushortx* __restrict__ Hb, float* __restrict__ ALS, float* __restrict__ ALD) {
    constexpr int K = 9, R = 2;
    const int c = threadIdx.x;
    const int lane = c & 63;
    const int wh = c >> 6;
    float wreg[K];
#pragma unroll
    for (int k = 0; k < K; ++k) wreg[k] = W[k * 256 + c];
    const float asv = a_s[c];
    const float adv = a_d[c];

    for (int row0 = blockIdx.x * R; row0 < NN; row0 += gridDim.x * R) {
        float p0[R], p1[R], p2[R];
#pragma unroll
        for (int r = 0; r < R; ++r) { p0[r] = p1[r] = p2[r] = 0.f; }
#pragma unroll
        for (int k = 0; k + 2 < K; k += 3) {
#pragma unroll
            for (int r = 0; r < R; ++r) {
                int rr = row0 + r; if (rr > NN - 1) rr = NN - 1;
                const float* xp = X + (size_t)rr * K;
                p0[r] = fmaf(wreg[k + 0], xp[k + 0], p0[r]);
                p1[r] = fmaf(wreg[k + 1], xp[k + 1], p1[r]);
                p2[r] = fmaf(wreg[k + 2], xp[k + 2], p2[r]);
            }
        }
#pragma unroll
        for (int r = 0; r < R; ++r) {
            int row = row0 + r;
            if (row < NN) {
                float hv = (p0[r] + p1[r]) + p2[r];
                Hb[(size_t)row * 256 + c] = f2bf(hv);
                float sv = hv * asv;
                float dv = hv * adv;
#pragma unroll
                for (int m = 32; m; m >>= 1) {
                    sv += __shfl_xor(sv, m, 64);
                    dv += __shfl_xor(dv, m, 64);
                }
                if (lane == 0) {
                    ALS[row * 4 + wh] = sv;
                    ALD[row * 4 + wh] = dv;
                }
            }
        }
    }
}

// ---------------- K=64 GEMM: W resident in 64 VGPRs ----------------

__global__ __launch_bounds__(256) void gemm_att64(
    const float* __restrict__ X, const float* __restrict__ W,
    const float* __restrict__ a_s, const float* __restrict__ a_d,
    ushortx* __restrict__ Hb, float* __restrict__ ALS, float* __restrict__ ALD) {
    constexpr int R = 4;
    const int c = threadIdx.x;
    const int lane = c & 63;
    const int wh = c >> 6;
    float4 w4[16];
#pragma unroll
    for (int q = 0; q < 16; ++q) {
        w4[q].x = W[(4 * q + 0) * 256 + c];
        w4[q].y = W[(4 * q + 1) * 256 + c];
        w4[q].z = W[(4 * q + 2) * 256 + c];
        w4[q].w = W[(4 * q + 3) * 256 + c];
    }
    const float asv = a_s[c];
    const float adv = a_d[c];

    for (int row0 = blockIdx.x * R; row0 < NN; row0 += gridDim.x * R) {
        float accA[R], accB[R];
#pragma unroll
        for (int r = 0; r < R; ++r) { accA[r] = accB[r] = 0.f; }
#pragma unroll
        for (int q = 0; q < 16; ++q) {
#pragma unroll
            for (int r = 0; r < R; ++r) {
                const float4 xv = ((const float4*)(X + (size_t)(row0 + r) * 64))[q];
                accA[r] = fmaf(w4[q].x, xv.x, accA[r]);
                accB[r] = fmaf(w4[q].y, xv.y, accB[r]);
                accA[r] = fmaf(w4[q].z, xv.z, accA[r]);
                accB[r] = fmaf(w4[q].w, xv.w, accB[r]);
            }
        }
#pragma unroll
        for (int r = 0; r < R; ++r) {
            int row = row0 + r;
            float hv = accA[r] + accB[r];
            Hb[(size_t)row * 256 + c] = f2bf(hv);
            float sv = hv * asv;
            float dv = hv * adv;
#pragma unroll
            for (int m = 32; m; m >>= 1) {
                sv += __shfl_xor(sv, m, 64);
                dv += __shfl_xor(dv, m, 64);
            }
            if (lane == 0) {
                ALS[row * 4 + wh] = sv;
                ALD[row * 4 + wh] = dv;
            }
        }
    }
}

// ---------------- fused softmax + aggregate (+ optional pooling) ------------
// bf16 Hb gather (8 B/lane/edge), unroll-4 inner loop (4 gathers in flight).
// Weight/index broadcast via the R7-proven __shfl scheme.

template <bool LAST>
__global__ __launch_bounds__(256) void aggregate6(
    const ushortx* __restrict__ Hb, const float* __restrict__ ALS,
    const float* __restrict__ ALD, const int* __restrict__ off,
    const int* __restrict__ csr_src, const float* __restrict__ bias,
    float* __restrict__ OUT, const int* __restrict__ batch,
    float* __restrict__ psum) {
    const int node = blockIdx.x * 4 + (threadIdx.x >> 6);
    const int l = threadIdx.x & 63;
    if (node >= NN) return;
    const int beg = off[node], end = off[node + 1];
    const int h = l >> 4;
    const uint2* hb2 = (const uint2*)Hb;   // row = 64 uint2 (256 bf16)
    const float4 aldv = ((const float4*)ALD)[node];
    float4 acc = {0.f, 0.f, 0.f, 0.f};
    float4 dsum = {0.f, 0.f, 0.f, 0.f};

    for (int j0 = beg; j0 < end; j0 += 64) {
        const int cnt = min(64, end - j0);
        const int jj = j0 + l;
        int sv = 0;
        float4 w4 = {0.f, 0.f, 0.f, 0.f};
        if (jj < end) {
            sv = csr_src[jj];
            float4 a = ((const float4*)ALS)[sv];
            float vx = a.x + aldv.x, vy = a.y + aldv.y,
                  vz = a.z + aldv.z, vw = a.w + aldv.w;
            vx = (vx >= 0.f) ? vx : 0.2f * vx;
            vy = (vy >= 0.f) ? vy : 0.2f * vy;
            vz = (vz >= 0.f) ? vz : 0.2f * vz;
            vw = (vw >= 0.f) ? vw : 0.2f * vw;
            w4.x = expf(vx); w4.y = expf(vy); w4.z = expf(vz); w4.w = expf(vw);
        }
        dsum.x += w4.x; dsum.y += w4.y; dsum.z += w4.z; dsum.w += w4.w;

        int t = 0;
        for (; t + 4 <= cnt; t += 4) {
            int s0 = __shfl(sv, t, 64);
            int s1 = __shfl(sv, t + 1, 64);
            int s2 = __shfl(sv, t + 2, 64);
            int s3 = __shfl(sv, t + 3, 64);
            uint2 u0 = hb2[(size_t)s0 * 64 + l];
            uint2 u1 = hb2[(size_t)s1 * 64 + l];
            uint2 u2 = hb2[(size_t)s2 * 64 + l];
            uint2 u3 = hb2[(size_t)s3 * 64 + l];
#pragma unroll
            for (int k = 0; k < 4; ++k) {
                int tt = t + k;
                float ax = __shfl(w4.x, tt, 64), ay = __shfl(w4.y, tt, 64),
                      az = __shfl(w4.z, tt, 64), aw = __shfl(w4.w, tt, 64);
                float w = (h == 0) ? ax : (h == 1) ? ay : (h == 2) ? az : aw;
                uint2 u = (k == 0) ? u0 : (k == 1) ? u1 : (k == 2) ? u2 : u3;
                float c0 = __uint_as_float(u.x << 16);
                float c1 = __uint_as_float(u.x & 0xFFFF0000u);
                float c2 = __uint_as_float(u.y << 16);
                float c3 = __uint_as_float(u.y & 0xFFFF0000u);
                acc.x = fmaf(w, c0, acc.x);
                acc.y = fmaf(w, c1, acc.y);
                acc.z = fmaf(w, c2, acc.z);
                acc.w = fmaf(w, c3, acc.w);
            }
        }
        for (; t < cnt; ++t) {
            int s0 = __shfl(sv, t, 64);
            float ax = __shfl(w4.x, t, 64), ay = __shfl(w4.y, t, 64),
                  az = __shfl(w4.z, t, 64), aw = __shfl(w4.w, t, 64);
            float w = (h == 0) ? ax : (h == 1) ? ay : (h == 2) ? az : aw;
            uint2 u = hb2[(size_t)s0 * 64 + l];
            float c0 = __uint_as_float(u.x << 16);
            float c1 = __uint_as_float(u.x & 0xFFFF0000u);
            float c2 = __uint_as_float(u.y << 16);
            float c3 = __uint_as_float(u.y & 0xFFFF0000u);
            acc.x = fmaf(w, c0, acc.x);
            acc.y = fmaf(w, c1, acc.y);
            acc.z = fmaf(w, c2, acc.z);
            acc.w = fmaf(w, c3, acc.w);
        }
    }

#pragma unroll
    for (int m = 32; m; m >>= 1) {
        dsum.x += __shfl_xor(dsum.x, m, 64);
        dsum.y += __shfl_xor(dsum.y, m, 64);
        dsum.z += __shfl_xor(dsum.z, m, 64);
        dsum.w += __shfl_xor(dsum.w, m, 64);
    }
    float den = (h == 0) ? dsum.x : (h == 1) ? dsum.y : (h == 2) ? dsum.z : dsum.w;
    const float inv = 1.f / (den + 1e-16f);
    acc.x *= inv; acc.y *= inv; acc.z *= inv; acc.w *= inv;

#pragma unroll
    for (int m = 16; m <= 32; m <<= 1) {
        acc.x += __shfl_xor(acc.x, m, 64);
        acc.y += __shfl_xor(acc.y, m, 64);
        acc.z += __shfl_xor(acc.z, m, 64);
        acc.w += __shfl_xor(acc.w, m, 64);
    }
    if (l < 16) {
        float4 b4 = ((const float4*)bias)[l];
        float4 o;
        o.x = fmaxf(acc.x * 0.25f + b4.x, 0.f);
        o.y = fmaxf(acc.y * 0.25f + b4.y, 0.f);
        o.z = fmaxf(acc.z * 0.25f + b4.z, 0.f);
        o.w = fmaxf(acc.w * 0.25f + b4.w, 0.f);
        if constexpr (LAST) {
            int g = batch[node];
            float* pp = psum + (size_t)g * 64 + l * 4;
            atomicAdd(pp + 0, o.x);
            atomicAdd(pp + 1, o.y);
            atomicAdd(pp + 2, o.z);
            atomicAdd(pp + 3, o.w);
        } else {
            ((float4*)(OUT + (size_t)node * 64))[l] = o;
        }
    }
}

// ---------------- final linear ----------------

__global__ void pool_out(const float* __restrict__ psum, const float* __restrict__ pcnt,
                         const float* __restrict__ lw, const float* __restrict__ lb,
                         float* __restrict__ out) {
    int g = blockIdx.x * 4 + (threadIdx.x >> 6);
    int lane = threadIdx.x & 63;
    if (g < GG) {
        float cnt = fmaxf(pcnt[g], 1.0f);
        float v = psum[(size_t)g * 64 + lane] / cnt * lw[lane];
#pragma unroll
        for (int m = 32; m; m >>= 1) v += __shfl_xor(v, m, 64);
        if (lane == 0) out[g] = v + lb[0];
    }
}

// ---------------- launch ----------------

extern "C" void kernel_launch(void* const* d_in, const int* in_sizes, int n_in,
                              void* d_out, int out_size, void* d_ws, size_t ws_size,
                              hipStream_t stream) {
    const float* x     = (const float*)d_in[0];
    const int*   ei    = (const int*)d_in[1];
    const int*   batch = (const int*)d_in[2];
    const float* W1  = (const float*)d_in[3];
    const float* as1 = (const float*)d_in[4];
    const float* ad1 = (const float*)d_in[5];
    const float* b1  = (const float*)d_in[6];
    const float* W2  = (const float*)d_in[7];
    const float* as2 = (const float*)d_in[8];
    const float* ad2 = (const float*)d_in[9];
    const float* b2  = (const float*)d_in[10];
    const float* W3  = (const float*)d_in[11];
    const float* as3 = (const float*)d_in[12];
    const float* ad3 = (const float*)d_in[13];
    const float* b3  = (const float*)d_in[14];
    const float* lw  = (const float*)d_in[15];
    const float* lb  = (const float*)d_in[16];
    float* out = (float*)d_out;

    char* p = (char*)d_ws;
    auto carve = [&](size_t bytes) -> void* {
        void* r = (void*)p;
        p += (bytes + 255) & ~(size_t)255;
        return r;
    };
    int*     off    = (int*)carve((NN + 4) * sizeof(int));
    int*     deg    = (int*)carve(NN * sizeof(int));
    int*     cursor = (int*)carve(NN * sizeof(int));
    int*     bsum   = (int*)carve(NB * sizeof(int));
    int*     boff   = (int*)carve(NB * sizeof(int));
    int*     csr    = (int*)carve((size_t)(EE + NN) * sizeof(int));
    ushortx* hbuf   = (ushortx*)carve((size_t)NN * 256 * sizeof(ushortx));
    float*   fa     = (float*)carve((size_t)NN * 64 * sizeof(float));
    float*   als    = (float*)carve((size_t)NN * 4 * sizeof(float));
    float*   ald    = (float*)carve((size_t)NN * 4 * sizeof(float));
    float*   psum   = (float*)carve((size_t)GG * 64 * sizeof(float));
    float*   pcnt   = (float*)carve(GG * sizeof(float));

    hipMemsetAsync(deg, 0, NN * sizeof(int), stream);
    hipMemsetAsync(cursor, 0, NN * sizeof(int), stream);
    hipMemsetAsync(psum, 0, (size_t)GG * 64 * sizeof(float), stream);
    hipMemsetAsync(pcnt, 0, GG * sizeof(float), stream);

    const int etot = EE + NN;
    const int eblocks = (etot + 255) / 256;
    hist_kernel<<<eblocks, 256, 0, stream>>>(ei, deg);
    node_count<<<(NN + 255) / 256, 256, 0, stream>>>(batch, pcnt);
    scan_blk<<<NB, 256, 0, stream>>>(deg, bsum);
    scan_mid<<<1, 128, 0, stream>>>(bsum, boff, off);
    scan_fin<<<NB, 256, 0, stream>>>(deg, boff, off);
    fill_kernel<<<eblocks, 256, 0, stream>>>(ei, off, cursor, csr);

    const int ablocks = (NN + 3) / 4;
    // layer 1
    gemm_att9<<<2048, 256, 0, stream>>>(x, W1, as1, ad1, hbuf, als, ald);
    aggregate6<false><<<ablocks, 256, 0, stream>>>(hbuf, als, ald, off, csr, b1,
                                                   fa, batch, psum);
    // layer 2
    gemm_att64<<<2048, 256, 0, stream>>>(fa, W2, as2, ad2, hbuf, als, ald);
    aggregate6<false><<<ablocks, 256, 0, stream>>>(hbuf, als, ald, off, csr, b2,
                                                   fa, batch, psum);
    // layer 3 (pooling fused)
    gemm_att64<<<2048, 256, 0, stream>>>(fa, W3, as3, ad3, hbuf, als, ald);
    aggregate6<true><<<ablocks, 256, 0, stream>>>(hbuf, als, ald, off, csr, b3,
                                                  nullptr, batch, psum);

    pool_out<<<(GG + 3) / 4, 256, 0, stream>>>(psum, pcnt, lw, lb, out);
}

// Round 9
// 616.512 us; speedup vs baseline: 1.6398x; 1.3391x over previous
//
#include <hip/hip_runtime.h>
#include <hip/hip_bf16.h>

#define NN 100000
#define EE 800000
#define HH 4
#define CC 64
#define GG 2000
#define NB 98           // scan blocks: ceil((NN/4)/256)

typedef unsigned short ushortx;
typedef __attribute__((ext_vector_type(8))) short short8;
typedef __attribute__((ext_vector_type(4))) float f32x4;

// ---------------- CSR build ----------------

__global__ void hist_kernel(const int* __restrict__ ei, int* __restrict__ deg) {
    int e = blockIdx.x * 256 + threadIdx.x;
    const int tot = EE + NN;
    if (e < tot) {
        int d = (e < EE) ? ei[EE + e] : (e - EE);
        atomicAdd(&deg[d], 1);
    }
}

__global__ void node_count(const int* __restrict__ batch, float* __restrict__ pcnt) {
    int n = blockIdx.x * 256 + threadIdx.x;
    if (n < NN) atomicAdd(&pcnt[batch[n]], 1.0f);
}

__global__ __launch_bounds__(256) void scan_blk(const int* __restrict__ deg,
                                                int* __restrict__ bsum) {
    const int t = threadIdx.x;
    const int idx4 = blockIdx.x * 256 + t;
    int4 v = {0, 0, 0, 0};
    if (idx4 < NN / 4) v = ((const int4*)deg)[idx4];
    int s = v.x + v.y + v.z + v.w;
#pragma unroll
    for (int m = 32; m; m >>= 1) s += __shfl_xor(s, m, 64);
    __shared__ int ws[4];
    if ((t & 63) == 0) ws[t >> 6] = s;
    __syncthreads();
    if (t == 0) bsum[blockIdx.x] = ws[0] + ws[1] + ws[2] + ws[3];
}

__global__ void scan_mid(const int* __restrict__ bsum, int* __restrict__ boff,
                         int* __restrict__ off) {
    __shared__ int sh[128];
    const int t = threadIdx.x;
    int v = (t < NB) ? bsum[t] : 0;
    sh[t] = v;
    __syncthreads();
    for (int d = 1; d < 128; d <<= 1) {
        int u = (t >= d) ? sh[t - d] : 0;
        __syncthreads();
        sh[t] += u;
        __syncthreads();
    }
    if (t < NB) boff[t] = sh[t] - v;
    if (t == NB - 1) off[NN] = sh[t];
}

__global__ __launch_bounds__(256) void scan_fin(const int* __restrict__ deg,
                                                const int* __restrict__ boff,
                                                int* __restrict__ off) {
    const int t = threadIdx.x;
    const int idx4 = blockIdx.x * 256 + t;
    int4 v = {0, 0, 0, 0};
    if (idx4 < NN / 4) v = ((const int4*)deg)[idx4];
    int s = v.x + v.y + v.z + v.w;
    const int lane = t & 63, w = t >> 6;
    int inc = s;
#pragma unroll
    for (int d = 1; d < 64; d <<= 1) {
        int u = __shfl_up(inc, d, 64);
        if (lane >= d) inc += u;
    }
    __shared__ int ws[4];
    if (lane == 63) ws[w] = inc;
    __syncthreads();
    int woff = 0;
    for (int i = 0; i < w; ++i) woff += ws[i];
    int excl = inc - s + woff + boff[blockIdx.x];
    if (idx4 < NN / 4) {
        int4 o;
        o.x = excl;
        o.y = o.x + v.x;
        o.z = o.y + v.y;
        o.w = o.z + v.z;
        ((int4*)off)[idx4] = o;
    }
}

__global__ void fill_kernel(const int* __restrict__ ei, const int* __restrict__ off,
                            int* __restrict__ cursor, int* __restrict__ csr_src) {
    int e = blockIdx.x * 256 + threadIdx.x;
    const int tot = EE + NN;
    if (e < tot) {
        int s, d;
        if (e < EE) { s = ei[e]; d = ei[EE + e]; }
        else        { s = e - EE; d = e - EE; }
        int p = off[d] + atomicAdd(&cursor[d], 1);
        csr_src[p] = s;
    }
}

__device__ __forceinline__ ushortx f2bf(float v) {
    __hip_bfloat16 b = __float2bfloat16(v);
    return *reinterpret_cast<ushortx*>(&b);
}

// ---------------- layer-1 GEMM (K=9), exact fp32 scalar path ----------------
// k-loop (step 3, bound k+2<K) covers k=0..8 COMPLETELY for K=9. No remainder.

__global__ __launch_bounds__(256) void gemm_att9(
    const float* __restrict__ X, const float* __restrict__ W,
    const float* __restrict__ a_s, const float* __restrict__ a_d,
    ushortx* __restrict__ Hb, float* __restrict__ ALS, float* __restrict__ ALD) {
    constexpr int K = 9, R = 2;
    const int c = threadIdx.x;
    const int lane = c & 63;
    const int wh = c >> 6;
    float wreg[K];
#pragma unroll
    for (int k = 0; k < K; ++k) wreg[k] = W[k * 256 + c];
    const float asv = a_s[c];
    const float adv = a_d[c];

    for (int row0 = blockIdx.x * R; row0 < NN; row0 += gridDim.x * R) {
        float p0[R], p1[R], p2[R];
#pragma unroll
        for (int r = 0; r < R; ++r) { p0[r] = p1[r] = p2[r] = 0.f; }
#pragma unroll
        for (int k = 0; k + 2 < K; k += 3) {
#pragma unroll
            for (int r = 0; r < R; ++r) {
                int rr = row0 + r; if (rr > NN - 1) rr = NN - 1;
                const float* xp = X + (size_t)rr * K;
                p0[r] = fmaf(wreg[k + 0], xp[k + 0], p0[r]);
                p1[r] = fmaf(wreg[k + 1], xp[k + 1], p1[r]);
                p2[r] = fmaf(wreg[k + 2], xp[k + 2], p2[r]);
            }
        }
#pragma unroll
        for (int r = 0; r < R; ++r) {
            int row = row0 + r;
            if (row < NN) {
                float hv = (p0[r] + p1[r]) + p2[r];
                Hb[(size_t)row * 256 + c] = f2bf(hv);
                float sv = hv * asv;
                float dv = hv * adv;
#pragma unroll
                for (int m = 32; m; m >>= 1) {
                    sv += __shfl_xor(sv, m, 64);
                    dv += __shfl_xor(dv, m, 64);
                }
                if (lane == 0) {
                    ALS[row * 4 + wh] = sv;
                    ALD[row * 4 + wh] = dv;
                }
            }
        }
    }
}

// ---------------- K=64 GEMM on matrix cores (bf16 MFMA) ----------------
// Verified layouts (learn_hip m89/m91/m120) for mfma_f32_16x16x32_bf16:
//   A[m=lane&15][k=(lane>>4)*8+j], B[k=(lane>>4)*8+j][n=lane&15],
//   D[row=(lane>>4)*4+reg][col=lane&15].
// Block = 4 waves; wave wv owns cols [wv*64, wv*64+64) = head wv, so the
// per-head ALS/ALD reduction is an intra-quad butterfly on fp32 accumulators.

__global__ __launch_bounds__(256) void gemm64_mfma(
    const float* __restrict__ X, const float* __restrict__ W,
    const float* __restrict__ a_s, const float* __restrict__ a_d,
    ushortx* __restrict__ Hb, float* __restrict__ ALS, float* __restrict__ ALD) {
    __shared__ ushortx wt[16][2][64][8];   // [ct][kh][lane][j]  (32 KB)
    __shared__ ushortx xt[16][72];         // strip rows, padded pitch
    __shared__ float asld[256], adld[256];
    __shared__ float alsw[4][16], aldw[4][16];   // [head][row]

    const int tid = threadIdx.x;
    const int l = tid & 63, wv = tid >> 6;
    const int n = l & 15, q = l >> 4;

    asld[tid] = a_s[tid];
    adld[tid] = a_d[tid];
    // stage W into B-fragment order (once per block)
    for (int k = 0; k < 64; ++k) {
        float v = W[k * 256 + tid];
        int ct = tid >> 4, nn = tid & 15;
        int kh = k >> 5, qq = (k >> 3) & 3, jj = k & 7;
        wt[ct][kh][qq * 16 + nn][jj] = f2bf(v);
    }
    __syncthreads();

    for (int row0 = blockIdx.x * 16; row0 < NN; row0 += gridDim.x * 16) {
        // stage X strip: 16 rows x 64 k, fp32 -> bf16
        {
            int r = tid >> 4, q4 = tid & 15;
            const float4 xv = *(const float4*)(X + (size_t)(row0 + r) * 64 + q4 * 4);
            ushortx* dst = &xt[r][q4 * 4];
            dst[0] = f2bf(xv.x); dst[1] = f2bf(xv.y);
            dst[2] = f2bf(xv.z); dst[3] = f2bf(xv.w);
        }
        __syncthreads();

        short8 a0 = *(const short8*)&xt[n][q * 8];        // k = 0..31 half
        short8 a1 = *(const short8*)&xt[n][32 + q * 8];   // k = 32..63 half

        float sv[4] = {0.f, 0.f, 0.f, 0.f};
        float dvv[4] = {0.f, 0.f, 0.f, 0.f};
#pragma unroll
        for (int ct = 0; ct < 4; ++ct) {
            const int ctg = wv * 4 + ct;
            short8 b0 = *(const short8*)&wt[ctg][0][l][0];
            short8 b1 = *(const short8*)&wt[ctg][1][l][0];
            f32x4 acc = {0.f, 0.f, 0.f, 0.f};
            acc = __builtin_amdgcn_mfma_f32_16x16x32_bf16(a0, b0, acc, 0, 0, 0);
            acc = __builtin_amdgcn_mfma_f32_16x16x32_bf16(a1, b1, acc, 0, 0, 0);
            const int col = ctg * 16 + n;
            const float asv = asld[col], adv = adld[col];
#pragma unroll
            for (int r = 0; r < 4; ++r) {
                const int row = row0 + q * 4 + r;
                Hb[(size_t)row * 256 + col] = f2bf(acc[r]);
                sv[r] = fmaf(acc[r], asv, sv[r]);
                dvv[r] = fmaf(acc[r], adv, dvv[r]);
            }
        }
        // reduce over n (16 lanes within quad) for this wave's head
#pragma unroll
        for (int m = 1; m <= 8; m <<= 1) {
#pragma unroll
            for (int r = 0; r < 4; ++r) {
                sv[r] += __shfl_xor(sv[r], m, 64);
                dvv[r] += __shfl_xor(dvv[r], m, 64);
            }
        }
        if (n == 0) {
#pragma unroll
            for (int r = 0; r < 4; ++r) {
                alsw[wv][q * 4 + r] = sv[r];
                aldw[wv][q * 4 + r] = dvv[r];
            }
        }
        __syncthreads();
        if (tid < 64) {
            int hh = tid & 3, rr = tid >> 2;
            ALS[(size_t)row0 * 4 + tid] = alsw[hh][rr];
            ALD[(size_t)row0 * 4 + tid] = aldw[hh][rr];
        }
        __syncthreads();
    }
}

// ---------------- fused softmax + aggregate (+ optional pooling) ------------

template <bool LAST>
__global__ __launch_bounds__(256) void aggregate6(
    const ushortx* __restrict__ Hb, const float* __restrict__ ALS,
    const float* __restrict__ ALD, const int* __restrict__ off,
    const int* __restrict__ csr_src, const float* __restrict__ bias,
    float* __restrict__ OUT, const int* __restrict__ batch,
    float* __restrict__ psum) {
    const int node = blockIdx.x * 4 + (threadIdx.x >> 6);
    const int l = threadIdx.x & 63;
    if (node >= NN) return;
    const int beg = off[node], end = off[node + 1];
    const int h = l >> 4;
    const uint2* hb2 = (const uint2*)Hb;   // row = 64 uint2 (256 bf16)
    const float4 aldv = ((const float4*)ALD)[node];
    float4 acc = {0.f, 0.f, 0.f, 0.f};
    float4 dsum = {0.f, 0.f, 0.f, 0.f};

    for (int j0 = beg; j0 < end; j0 += 64) {
        const int cnt = min(64, end - j0);
        const int jj = j0 + l;
        int sv = 0;
        float4 w4 = {0.f, 0.f, 0.f, 0.f};
        if (jj < end) {
            sv = csr_src[jj];
            float4 a = ((const float4*)ALS)[sv];
            float vx = a.x + aldv.x, vy = a.y + aldv.y,
                  vz = a.z + aldv.z, vw = a.w + aldv.w;
            vx = (vx >= 0.f) ? vx : 0.2f * vx;
            vy = (vy >= 0.f) ? vy : 0.2f * vy;
            vz = (vz >= 0.f) ? vz : 0.2f * vz;
            vw = (vw >= 0.f) ? vw : 0.2f * vw;
            w4.x = expf(vx); w4.y = expf(vy); w4.z = expf(vz); w4.w = expf(vw);
        }
        dsum.x += w4.x; dsum.y += w4.y; dsum.z += w4.z; dsum.w += w4.w;

        int t = 0;
        for (; t + 4 <= cnt; t += 4) {
            int s0 = __shfl(sv, t, 64);
            int s1 = __shfl(sv, t + 1, 64);
            int s2 = __shfl(sv, t + 2, 64);
            int s3 = __shfl(sv, t + 3, 64);
            uint2 u0 = hb2[(size_t)s0 * 64 + l];
            uint2 u1 = hb2[(size_t)s1 * 64 + l];
            uint2 u2 = hb2[(size_t)s2 * 64 + l];
            uint2 u3 = hb2[(size_t)s3 * 64 + l];
#pragma unroll
            for (int k = 0; k < 4; ++k) {
                int tt = t + k;
                float ax = __shfl(w4.x, tt, 64), ay = __shfl(w4.y, tt, 64),
                      az = __shfl(w4.z, tt, 64), aw = __shfl(w4.w, tt, 64);
                float w = (h == 0) ? ax : (h == 1) ? ay : (h == 2) ? az : aw;
                uint2 u = (k == 0) ? u0 : (k == 1) ? u1 : (k == 2) ? u2 : u3;
                float c0 = __uint_as_float(u.x << 16);
                float c1 = __uint_as_float(u.x & 0xFFFF0000u);
                float c2 = __uint_as_float(u.y << 16);
                float c3 = __uint_as_float(u.y & 0xFFFF0000u);
                acc.x = fmaf(w, c0, acc.x);
                acc.y = fmaf(w, c1, acc.y);
                acc.z = fmaf(w, c2, acc.z);
                acc.w = fmaf(w, c3, acc.w);
            }
        }
        for (; t < cnt; ++t) {
            int s0 = __shfl(sv, t, 64);
            float ax = __shfl(w4.x, t, 64), ay = __shfl(w4.y, t, 64),
                  az = __shfl(w4.z, t, 64), aw = __shfl(w4.w, t, 64);
            float w = (h == 0) ? ax : (h == 1) ? ay : (h == 2) ? az : aw;
            uint2 u = hb2[(size_t)s0 * 64 + l];
            float c0 = __uint_as_float(u.x << 16);
            float c1 = __uint_as_float(u.x & 0xFFFF0000u);
            float c2 = __uint_as_float(u.y << 16);
            float c3 = __uint_as_float(u.y & 0xFFFF0000u);
            acc.x = fmaf(w, c0, acc.x);
            acc.y = fmaf(w, c1, acc.y);
            acc.z = fmaf(w, c2, acc.z);
            acc.w = fmaf(w, c3, acc.w);
        }
    }

#pragma unroll
    for (int m = 32; m; m >>= 1) {
        dsum.x += __shfl_xor(dsum.x, m, 64);
        dsum.y += __shfl_xor(dsum.y, m, 64);
        dsum.z += __shfl_xor(dsum.z, m, 64);
        dsum.w += __shfl_xor(dsum.w, m, 64);
    }
    float den = (h == 0) ? dsum.x : (h == 1) ? dsum.y : (h == 2) ? dsum.z : dsum.w;
    const float inv = 1.f / (den + 1e-16f);
    acc.x *= inv; acc.y *= inv; acc.z *= inv; acc.w *= inv;

#pragma unroll
    for (int m = 16; m <= 32; m <<= 1) {
        acc.x += __shfl_xor(acc.x, m, 64);
        acc.y += __shfl_xor(acc.y, m, 64);
        acc.z += __shfl_xor(acc.z, m, 64);
        acc.w += __shfl_xor(acc.w, m, 64);
    }
    if (l < 16) {
        float4 b4 = ((const float4*)bias)[l];
        float4 o;
        o.x = fmaxf(acc.x * 0.25f + b4.x, 0.f);
        o.y = fmaxf(acc.y * 0.25f + b4.y, 0.f);
        o.z = fmaxf(acc.z * 0.25f + b4.z, 0.f);
        o.w = fmaxf(acc.w * 0.25f + b4.w, 0.f);
        if constexpr (LAST) {
            int g = batch[node];
            float* pp = psum + (size_t)g * 64 + l * 4;
            atomicAdd(pp + 0, o.x);
            atomicAdd(pp + 1, o.y);
            atomicAdd(pp + 2, o.z);
            atomicAdd(pp + 3, o.w);
        } else {
            ((float4*)(OUT + (size_t)node * 64))[l] = o;
        }
    }
}

// ---------------- final linear ----------------

__global__ void pool_out(const float* __restrict__ psum, const float* __restrict__ pcnt,
                         const float* __restrict__ lw, const float* __restrict__ lb,
                         float* __restrict__ out) {
    int g = blockIdx.x * 4 + (threadIdx.x >> 6);
    int lane = threadIdx.x & 63;
    if (g < GG) {
        float cnt = fmaxf(pcnt[g], 1.0f);
        float v = psum[(size_t)g * 64 + lane] / cnt * lw[lane];
#pragma unroll
        for (int m = 32; m; m >>= 1) v += __shfl_xor(v, m, 64);
        if (lane == 0) out[g] = v + lb[0];
    }
}

// ---------------- launch ----------------

extern "C" void kernel_launch(void* const* d_in, const int* in_sizes, int n_in,
                              void* d_out, int out_size, void* d_ws, size_t ws_size,
                              hipStream_t stream) {
    const float* x     = (const float*)d_in[0];
    const int*   ei    = (const int*)d_in[1];
    const int*   batch = (const int*)d_in[2];
    const float* W1  = (const float*)d_in[3];
    const float* as1 = (const float*)d_in[4];
    const float* ad1 = (const float*)d_in[5];
    const float* b1  = (const float*)d_in[6];
    const float* W2  = (const float*)d_in[7];
    const float* as2 = (const float*)d_in[8];
    const float* ad2 = (const float*)d_in[9];
    const float* b2  = (const float*)d_in[10];
    const float* W3  = (const float*)d_in[11];
    const float* as3 = (const float*)d_in[12];
    const float* ad3 = (const float*)d_in[13];
    const float* b3  = (const float*)d_in[14];
    const float* lw  = (const float*)d_in[15];
    const float* lb  = (const float*)d_in[16];
    float* out = (float*)d_out;

    char* p = (char*)d_ws;
    auto carve = [&](size_t bytes) -> void* {
        void* r = (void*)p;
        p += (bytes + 255) & ~(size_t)255;
        return r;
    };
    int*     off    = (int*)carve((NN + 4) * sizeof(int));
    int*     deg    = (int*)carve(NN * sizeof(int));
    int*     cursor = (int*)carve(NN * sizeof(int));
    int*     bsum   = (int*)carve(NB * sizeof(int));
    int*     boff   = (int*)carve(NB * sizeof(int));
    int*     csr    = (int*)carve((size_t)(EE + NN) * sizeof(int));
    ushortx* hbuf   = (ushortx*)carve((size_t)NN * 256 * sizeof(ushortx));
    float*   fa     = (float*)carve((size_t)NN * 64 * sizeof(float));
    float*   als    = (float*)carve((size_t)NN * 4 * sizeof(float));
    float*   ald    = (float*)carve((size_t)NN * 4 * sizeof(float));
    float*   psum   = (float*)carve((size_t)GG * 64 * sizeof(float));
    float*   pcnt   = (float*)carve(GG * sizeof(float));

    hipMemsetAsync(deg, 0, NN * sizeof(int), stream);
    hipMemsetAsync(cursor, 0, NN * sizeof(int), stream);
    hipMemsetAsync(psum, 0, (size_t)GG * 64 * sizeof(float), stream);
    hipMemsetAsync(pcnt, 0, GG * sizeof(float), stream);

    const int etot = EE + NN;
    const int eblocks = (etot + 255) / 256;
    hist_kernel<<<eblocks, 256, 0, stream>>>(ei, deg);
    node_count<<<(NN + 255) / 256, 256, 0, stream>>>(batch, pcnt);
    scan_blk<<<NB, 256, 0, stream>>>(deg, bsum);
    scan_mid<<<1, 128, 0, stream>>>(bsum, boff, off);
    scan_fin<<<NB, 256, 0, stream>>>(deg, boff, off);
    fill_kernel<<<eblocks, 256, 0, stream>>>(ei, off, cursor, csr);

    const int ablocks = (NN + 3) / 4;
    // layer 1 (exact fp32 path, K=9)
    gemm_att9<<<2048, 256, 0, stream>>>(x, W1, as1, ad1, hbuf, als, ald);
    aggregate6<false><<<ablocks, 256, 0, stream>>>(hbuf, als, ald, off, csr, b1,
                                                   fa, batch, psum);
    // layer 2 (MFMA)
    gemm64_mfma<<<1024, 256, 0, stream>>>(fa, W2, as2, ad2, hbuf, als, ald);
    aggregate6<false><<<ablocks, 256, 0, stream>>>(hbuf, als, ald, off, csr, b2,
                                                   fa, batch, psum);
    // layer 3 (MFMA, pooling fused)
    gemm64_mfma<<<1024, 256, 0, stream>>>(fa, W3, as3, ad3, hbuf, als, ald);
    aggregate6<true><<<ablocks, 256, 0, stream>>>(hbuf, als, ald, off, csr, b3,
                                                  nullptr, batch, psum);

    pool_out<<<(GG + 3) / 4, 256, 0, stream>>>(psum, pcnt, lw, lb, out);
}